// Round 7
// baseline (150.950 us; speedup 1.0000x reference)
//
#include <hip/hip_runtime.h>
#include <hip/hip_bf16.h>

// Problem dims (fixed by the reference setup_inputs)
#define BB 8
#define TT 4096
#define SS 256
#define DD 512

typedef __attribute__((ext_vector_type(8))) short short8;
typedef __attribute__((ext_vector_type(4))) float floatx4;
typedef __attribute__((ext_vector_type(4))) int intx4;

// Packed RNE f32x2 -> bf16x2 (v_cvt_pk_bf16_f32 on gfx950).
__device__ inline int pk2(float a, float b) {
  __hip_bfloat162 h = __float22bfloat162_rn(make_float2(a, b));
  int r;
  __builtin_memcpy(&r, &h, 4);
  return r;
}

// Pack 8 consecutive-k f32 values into a bf16 MFMA fragment.
__device__ inline short8 cvt8(float4 f0, float4 f1) {
  intx4 p;
  p[0] = pk2(f0.x, f0.y);
  p[1] = pk2(f0.z, f0.w);
  p[2] = pk2(f1.x, f1.y);
  p[3] = pk2(f1.z, f1.w);
  return __builtin_bit_cast(short8, p);
}

// Fully fused cosine scorer:
//   C[b] = diag(1/||x||) * (bf16(X[b]) * bf16(Y[b])^T) * diag(1/||y||)
// 128x128 tile, BK=64 f32.
//  - A (xs, 64 MB streamed once): async global_load_lds width=16 into a
//    single 32 KB LDS buffer, XOR-16 swizzled (16B-slot s of a row holds
//    logical block s ^ (row&15)) -> ds_read_b128 frags bank-uniform.
//    Only A is barrier-protected; the drain region halved vs round 6 and
//    LDS 33 KB (vs 66.5) lets ~3 blocks/CU interleave their barriers.
//  - B (spk, 512 KB/batch, L2/L3-resident): loaded global->VGPR per
//    fragment, software-prefetched per ks-half — no LDS, no barrier
//    dependency, compiler schedules fine-grained vmcnt.
// Per-row sumsq via gram MFMAs (diag of mfma(f,f) = row sumsq; frag layout
// k-symmetric): wm==wn waves accumulate A-grams, wm!=wn waves B-grams.
__global__ __launch_bounds__(256) void cos_fused_kernel(
    const float* __restrict__ xs, const float* __restrict__ spk,
    float* __restrict__ out) {
  __shared__ float sA[128 * 64];
  __shared__ float scX[128];
  __shared__ float scY[128];

  const int tid = threadIdx.x;
  const int wave = tid >> 6;
  const int lane = tid & 63;
  const int tn = blockIdx.x;  // 0..1
  const int tm = blockIdx.y;  // 0..31
  const int b = blockIdx.z;   // 0..7

  const float* Abase = xs + ((size_t)b * TT + tm * 128) * DD;
  const float* Bbase = spk + ((size_t)b * SS + tn * 128) * DD;

  floatx4 acc[4][4];
#pragma unroll
  for (int i = 0; i < 4; i++)
#pragma unroll
    for (int j = 0; j < 4; j++) acc[i][j] = (floatx4){0.f, 0.f, 0.f, 0.f};
  floatx4 accG[4];  // gram accumulators (A-rows if wm==wn else B-rows)
#pragma unroll
  for (int i = 0; i < 4; i++) accG[i] = (floatx4){0.f, 0.f, 0.f, 0.f};

  const int wm = wave >> 1;
  const int wn = wave & 1;
  const int quad = lane >> 4;
  const int l15 = lane & 15;
  const bool gramA = (wm == wn);

  // Per-lane B fragment row pointers (row = wn*64 + in*16 + l15), offset to
  // this lane's k-chunk base (quad*8 f32 within each 32-f32 ks-half).
  const float* bp[4];
#pragma unroll
  for (int in = 0; in < 4; in++)
    bp[in] = Bbase + (size_t)(wn * 64 + in * 16 + l15) * DD + quad * 8;

  // A staging map: 16B unit s = j*256 + tid; row = s>>4 (16 units/row);
  // slot = s&15 holds logical block (slot ^ (row&15)).
  int aoff[8];
#pragma unroll
  for (int j = 0; j < 8; j++) {
    int s = j * 256 + tid;
    int row = s >> 4;
    int blk = (s & 15) ^ (row & 15);
    aoff[j] = row * DD + blk * 4;
  }

  for (int kt = 0; kt < DD / 64; ++kt) {
    // Issue A DMA for this kt.
#pragma unroll
    for (int j = 0; j < 8; j++) {
      const float* ga = Abase + aoff[j] + kt * 64;
      __builtin_amdgcn_global_load_lds(
          (const __attribute__((address_space(1))) unsigned int*)ga,
          (__attribute__((address_space(3))) unsigned int*)(sA +
              (j * 256 + wave * 64) * 4),
          16, 0, 0);
    }
    // Prefetch B for ks=0 (global->reg; overlaps the A DMA drain).
    float4 b0[4][2];
#pragma unroll
    for (int in = 0; in < 4; in++) {
      const float* p = bp[in] + kt * 64;
      b0[in][0] = *(const float4*)(p);
      b0[in][1] = *(const float4*)(p + 4);
    }
    __syncthreads();

#pragma unroll
    for (int ks = 0; ks < 2; ks++) {
      short8 af[4], bfr[4];
      const int b0s = ks * 8 + quad * 2;  // first 16B block of A frag
#pragma unroll
      for (int im = 0; im < 4; im++) {
        int row = wm * 64 + im * 16 + l15;
        int s0 = b0s ^ (row & 15);
        int s1 = (b0s + 1) ^ (row & 15);
        float4 f0 = *(const float4*)(sA + row * 64 + s0 * 4);
        float4 f1 = *(const float4*)(sA + row * 64 + s1 * 4);
        af[im] = cvt8(f0, f1);
      }
#pragma unroll
      for (int in = 0; in < 4; in++) bfr[in] = cvt8(b0[in][0], b0[in][1]);
      if (ks == 0) {
        // Prefetch B for ks=1 while ks=0 MFMAs run.
#pragma unroll
        for (int in = 0; in < 4; in++) {
          const float* p = bp[in] + kt * 64 + 32;
          b0[in][0] = *(const float4*)(p);
          b0[in][1] = *(const float4*)(p + 4);
        }
      }
#pragma unroll
      for (int im = 0; im < 4; im++)
#pragma unroll
        for (int in = 0; in < 4; in++)
          acc[im][in] = __builtin_amdgcn_mfma_f32_16x16x32_bf16(
              af[im], bfr[in], acc[im][in], 0, 0, 0);
      if (gramA) {
#pragma unroll
        for (int im = 0; im < 4; im++)
          accG[im] = __builtin_amdgcn_mfma_f32_16x16x32_bf16(
              af[im], af[im], accG[im], 0, 0, 0);
      } else {
#pragma unroll
        for (int in = 0; in < 4; in++)
          accG[in] = __builtin_amdgcn_mfma_f32_16x16x32_bf16(
              bfr[in], bfr[in], accG[in], 0, 0, 0);
      }
    }
    __syncthreads();
  }

  // Extract gram diagonals -> inverse norms. C/D layout: col = l15,
  // row = quad*4 + r; diagonal element d held by lane with l15 == d,
  // quad == d>>2, at reg r = d&3.
  if (quad == (l15 >> 2)) {
#pragma unroll
    for (int i = 0; i < 4; i++) {
      float inv = 1.0f / fmaxf(sqrtf(accG[i][l15 & 3]), 1e-8f);
      if (gramA)
        scX[wm * 64 + i * 16 + l15] = inv;  // waves (0,0),(1,1): rows 0..127
      else
        scY[wn * 64 + i * 16 + l15] = inv;  // waves (0,1),(1,0): cols 0..127
    }
  }
  __syncthreads();

  // Epilogue: apply cosine scales (dot * (1/||x||) * (1/||y||)).
  float* Obase = out + ((size_t)b * TT + tm * 128) * SS + tn * 128;
#pragma unroll
  for (int im = 0; im < 4; im++) {
#pragma unroll
    for (int in = 0; in < 4; in++) {
      int col = wn * 64 + in * 16 + l15;
      float yv = scY[col];
#pragma unroll
      for (int r = 0; r < 4; r++) {
        int row = wm * 64 + im * 16 + quad * 4 + r;
        Obase[row * SS + col] = acc[im][in][r] * scX[row] * yv;
      }
    }
  }
}

extern "C" void kernel_launch(void* const* d_in, const int* in_sizes, int n_in,
                              void* d_out, int out_size, void* d_ws,
                              size_t ws_size, hipStream_t stream) {
  const float* xs = (const float*)d_in[0];   // (8,4096,512) f32
  const float* spk = (const float*)d_in[1];  // (8,256,512) f32
  float* out = (float*)d_out;                // (8,4096,256) f32

  hipLaunchKernelGGL(cos_fused_kernel, dim3(SS / 128, TT / 128, BB), dim3(256),
                     0, stream, xs, spk, out);
}

// Round 8
// 124.918 us; speedup vs baseline: 1.2084x; 1.2084x over previous
//
#include <hip/hip_runtime.h>
#include <hip/hip_bf16.h>

// Problem dims (fixed by the reference setup_inputs)
#define BB 8
#define TT 4096
#define SS 256
#define DD 512

typedef __attribute__((ext_vector_type(8))) short short8;
typedef __attribute__((ext_vector_type(4))) float floatx4;
typedef __attribute__((ext_vector_type(4))) int intx4;

// Packed RNE f32x2 -> bf16x2 (v_cvt_pk_bf16_f32 on gfx950).
__device__ inline int pk2(float a, float b) {
  __hip_bfloat162 h = __float22bfloat162_rn(make_float2(a, b));
  int r;
  __builtin_memcpy(&r, &h, 4);
  return r;
}

// Pack 8 consecutive-k f32 values into a bf16 MFMA fragment.
__device__ inline short8 cvt8(float4 f0, float4 f1) {
  intx4 p;
  p[0] = pk2(f0.x, f0.y);
  p[1] = pk2(f0.z, f0.w);
  p[2] = pk2(f1.x, f1.y);
  p[3] = pk2(f1.z, f1.w);
  return __builtin_bit_cast(short8, p);
}

// Fully fused cosine scorer:
//   C[b] = diag(1/||x||) * (bf16(X[b]) * bf16(Y[b])^T) * diag(1/||y||)
// 128x128 tile, BK=32 f32, PING-PONG double-buffered LDS with ONE barrier
// per kt:
//   prologue: DMA -> buf0
//   loop kt : __syncthreads()  (its vmcnt(0) waits only cur's DMA)
//             issue DMA -> buf[kt+1]   (in flight during all of kt's compute)
//             ds_read/cvt/mfma from buf[kt]
// Round 6 issued the DMA right before the draining barrier (zero overlap);
// round 7 proved per-lane global B loads are a 64-way scatter disaster —
// both operands stay on the coalesced global_load_lds path.
// XOR-8 swizzle: LDS 16B-slot s of a row holds logical block s ^ (row&7)
// -> ds_read_b128 frag reads are 2-way-bank-aliased (free).
// Per-row sumsq via gram MFMAs (diag of mfma(f,f) = row sumsq; frag layout
// k-symmetric): wm==wn waves accumulate A-grams, wm!=wn waves B-grams.
__global__ __launch_bounds__(256) void cos_fused_kernel(
    const float* __restrict__ xs, const float* __restrict__ spk,
    float* __restrict__ out) {
  __shared__ float sA[2][128 * 32];
  __shared__ float sB[2][128 * 32];
  __shared__ float scX[128];
  __shared__ float scY[128];

  const int tid = threadIdx.x;
  const int wave = tid >> 6;
  const int lane = tid & 63;
  const int tn = blockIdx.x;  // 0..1
  const int tm = blockIdx.y;  // 0..31
  const int b = blockIdx.z;   // 0..7

  const float* Abase = xs + ((size_t)b * TT + tm * 128) * DD;
  const float* Bbase = spk + ((size_t)b * SS + tn * 128) * DD;

  floatx4 acc[4][4];
#pragma unroll
  for (int i = 0; i < 4; i++)
#pragma unroll
    for (int j = 0; j < 4; j++) acc[i][j] = (floatx4){0.f, 0.f, 0.f, 0.f};
  floatx4 accG[4];  // gram accumulators (A-rows if wm==wn else B-rows)
#pragma unroll
  for (int i = 0; i < 4; i++) accG[i] = (floatx4){0.f, 0.f, 0.f, 0.f};

  const int wm = wave >> 1;
  const int wn = wave & 1;
  const int quad = lane >> 4;
  const int l15 = lane & 15;
  const bool gramA = (wm == wn);

  // Staging map (per kt: 128 rows x 32 f32 = 1024 16B-units per matrix,
  // 4 units/thread). Unit s: row = s>>3 (8 units/row); slot s&7 holds
  // logical block (s&7) ^ (row&7).
  int aoff[4];
#pragma unroll
  for (int j = 0; j < 4; j++) {
    int s = j * 256 + tid;
    int row = s >> 3;
    int blk = (s & 7) ^ (row & 7);
    aoff[j] = row * DD + blk * 4;
  }

  // Prologue: DMA for kt=0 into buffer 0.
#pragma unroll
  for (int j = 0; j < 4; j++) {
    __builtin_amdgcn_global_load_lds(
        (const __attribute__((address_space(1))) unsigned int*)(Abase +
            aoff[j]),
        (__attribute__((address_space(3))) unsigned int*)(&sA[0][0] +
            (j * 256 + wave * 64) * 4),
        16, 0, 0);
    __builtin_amdgcn_global_load_lds(
        (const __attribute__((address_space(1))) unsigned int*)(Bbase +
            aoff[j]),
        (__attribute__((address_space(3))) unsigned int*)(&sB[0][0] +
            (j * 256 + wave * 64) * 4),
        16, 0, 0);
  }

  for (int kt = 0; kt < DD / 32; ++kt) {
    __syncthreads();  // vmcnt(0): waits this wave's DMA for buf[kt&1] only

    if (kt + 1 < DD / 32) {
      const int nb = (kt + 1) & 1;
#pragma unroll
      for (int j = 0; j < 4; j++) {
        __builtin_amdgcn_global_load_lds(
            (const __attribute__((address_space(1))) unsigned int*)(Abase +
                aoff[j] + (kt + 1) * 32),
            (__attribute__((address_space(3))) unsigned int*)(&sA[nb][0] +
                (j * 256 + wave * 64) * 4),
            16, 0, 0);
        __builtin_amdgcn_global_load_lds(
            (const __attribute__((address_space(1))) unsigned int*)(Bbase +
                aoff[j] + (kt + 1) * 32),
            (__attribute__((address_space(3))) unsigned int*)(&sB[nb][0] +
                (j * 256 + wave * 64) * 4),
            16, 0, 0);
      }
    }

    const float* cA = &sA[kt & 1][0];
    const float* cB = &sB[kt & 1][0];
    short8 af[4], bfr[4];
    const int b0s = quad * 2;  // first 16B block of the frag's 8 f32
#pragma unroll
    for (int im = 0; im < 4; im++) {
      int row = wm * 64 + im * 16 + l15;
      int s0 = b0s ^ (row & 7);
      int s1 = (b0s + 1) ^ (row & 7);
      float4 f0 = *(const float4*)(cA + row * 32 + s0 * 4);
      float4 f1 = *(const float4*)(cA + row * 32 + s1 * 4);
      af[im] = cvt8(f0, f1);
    }
#pragma unroll
    for (int in = 0; in < 4; in++) {
      int row = wn * 64 + in * 16 + l15;
      int s0 = b0s ^ (row & 7);
      int s1 = (b0s + 1) ^ (row & 7);
      float4 f0 = *(const float4*)(cB + row * 32 + s0 * 4);
      float4 f1 = *(const float4*)(cB + row * 32 + s1 * 4);
      bfr[in] = cvt8(f0, f1);
    }
#pragma unroll
    for (int im = 0; im < 4; im++)
#pragma unroll
      for (int in = 0; in < 4; in++)
        acc[im][in] = __builtin_amdgcn_mfma_f32_16x16x32_bf16(
            af[im], bfr[in], acc[im][in], 0, 0, 0);
    if (gramA) {
#pragma unroll
      for (int im = 0; im < 4; im++)
        accG[im] = __builtin_amdgcn_mfma_f32_16x16x32_bf16(
            af[im], af[im], accG[im], 0, 0, 0);
    } else {
#pragma unroll
      for (int in = 0; in < 4; in++)
        accG[in] = __builtin_amdgcn_mfma_f32_16x16x32_bf16(
            bfr[in], bfr[in], accG[in], 0, 0, 0);
    }
  }

  // Extract gram diagonals -> inverse norms. C/D layout: col = l15,
  // row = quad*4 + r; diagonal element d held by lane with l15 == d,
  // quad == d>>2, at reg r = d&3.
  if (quad == (l15 >> 2)) {
#pragma unroll
    for (int i = 0; i < 4; i++) {
      float inv = 1.0f / fmaxf(sqrtf(accG[i][l15 & 3]), 1e-8f);
      if (gramA)
        scX[wm * 64 + i * 16 + l15] = inv;  // waves (0,0),(1,1): rows 0..127
      else
        scY[wn * 64 + i * 16 + l15] = inv;  // waves (0,1),(1,0): cols 0..127
    }
  }
  __syncthreads();

  // Epilogue: apply cosine scales (dot * (1/||x||) * (1/||y||)).
  float* Obase = out + ((size_t)b * TT + tm * 128) * SS + tn * 128;
#pragma unroll
  for (int im = 0; im < 4; im++) {
#pragma unroll
    for (int in = 0; in < 4; in++) {
      int col = wn * 64 + in * 16 + l15;
      float yv = scY[col];
#pragma unroll
      for (int r = 0; r < 4; r++) {
        int row = wm * 64 + im * 16 + quad * 4 + r;
        Obase[row * SS + col] = acc[im][in][r] * scX[row] * yv;
      }
    }
  }
}

extern "C" void kernel_launch(void* const* d_in, const int* in_sizes, int n_in,
                              void* d_out, int out_size, void* d_ws,
                              size_t ws_size, hipStream_t stream) {
  const float* xs = (const float*)d_in[0];   // (8,4096,512) f32
  const float* spk = (const float*)d_in[1];  // (8,256,512) f32
  float* out = (float*)d_out;                // (8,4096,256) f32

  hipLaunchKernelGGL(cos_fused_kernel, dim3(SS / 128, TT / 128, BB), dim3(256),
                     0, stream, xs, spk, out);
}

// Round 10
// 116.082 us; speedup vs baseline: 1.3004x; 1.0761x over previous
//
#include <hip/hip_runtime.h>
#include <hip/hip_bf16.h>

// Problem dims (fixed by the reference setup_inputs)
#define BB 8
#define TT 4096
#define SS 256
#define DD 512

typedef __attribute__((ext_vector_type(8))) short short8;
typedef __attribute__((ext_vector_type(4))) float floatx4;
typedef __attribute__((ext_vector_type(4))) int intx4;

// Packed RNE f32x2 -> bf16x2 (v_cvt_pk_bf16_f32 on gfx950).
__device__ inline int pk2(float a, float b) {
  __hip_bfloat162 h = __float22bfloat162_rn(make_float2(a, b));
  int r;
  __builtin_memcpy(&r, &h, 4);
  return r;
}

// Pack 8 consecutive-k f32 values into a bf16 MFMA fragment.
__device__ inline short8 cvt8(float4 f0, float4 f1) {
  intx4 p;
  p[0] = pk2(f0.x, f0.y);
  p[1] = pk2(f0.z, f0.w);
  p[2] = pk2(f1.x, f1.y);
  p[3] = pk2(f1.z, f1.w);
  return __builtin_bit_cast(short8, p);
}

// K1: pack spk (8,256,512) f32 -> bf16 in global_load_lds DMA order.
// Region (b, tn, kh): 128 cols x 128 k as 2048 16B-units; unit u:
// row(col) = u>>4, stored slot = u&15 holding logical k-block
// (u&15) ^ (row&15)  [XOR-16 swizzle baked in; 256-B LDS rows = the
// measured-conflict-free pattern]. 64 regions x 32 KB = 2 MB in ws.
__global__ __launch_bounds__(256) void cos_packB_kernel(
    const float* __restrict__ spk, short* __restrict__ bp) {
  const int idx = blockIdx.x;      // 64 regions
  const int b = idx >> 3;          // 0..7
  const int tn = (idx >> 2) & 1;   // 0..1
  const int kh = idx & 3;          // 0..3 (k-quarter of 128)
  const int tid = threadIdx.x;
  short* dst = bp + (size_t)idx * 2048 * 8;
#pragma unroll
  for (int j = 0; j < 8; j++) {
    int u = j * 256 + tid;
    int row = u >> 4;
    int kblk = (u & 15) ^ (row & 15);
    const float* src =
        spk + ((size_t)(b * SS + tn * 128 + row)) * DD + kh * 128 + kblk * 8;
    float4 f0 = *(const float4*)src;
    float4 f1 = *(const float4*)(src + 4);
    short8 o = cvt8(f0, f1);
    *(short8*)(dst + (size_t)u * 8) = o;
  }
}

// K2: fused cosine scorer,
//   C[b] = diag(1/||x||) * (bf16(X[b]) * bf16(Y[b])^T) * diag(1/||y||)
// 128x128 tile. A: f32, BK=64, async global_load_lds width=16, XOR-16
// swizzle (round-6 proven conflict-free). B: pre-packed bf16 (K1), staged
// 128-k at a time (32 KB, every other kt) via contiguous DMA — halves B's
// staged bytes (kernel is total-staged-VMEM-byte limited per round-8 model).
// NOTE round-9 bug: the B DMA source pointer must be PER-LANE
// (base + unit(j,wave,lane)*16B); global_load_lds scatters lane i to
// LDS base + i*16 but reads each lane's own global address.
// B-frag = ONE ds_read_b128, no cvt. Per-row sumsq via gram MFMAs
// (diag of mfma(f,f) = row sumsq): wm==wn waves A-grams, others B-grams.
__global__ __launch_bounds__(256) void cos_fused_kernel(
    const float* __restrict__ xs, const short* __restrict__ bp,
    float* __restrict__ out) {
  __shared__ float sA[128 * 64];    // 32 KB: A tile, 64 k (f32)
  __shared__ short sB[128 * 128];   // 32 KB: B tile, 128 k (bf16)
  __shared__ float scX[128];
  __shared__ float scY[128];

  const int tid = threadIdx.x;
  const int wave = tid >> 6;
  const int lane = tid & 63;
  const int tn = blockIdx.x;  // 0..1
  const int tm = blockIdx.y;  // 0..31
  const int b = blockIdx.z;   // 0..7

  const float* Abase = xs + ((size_t)b * TT + tm * 128) * DD;
  const short* Bbase = bp + ((size_t)(b * 2 + tn) * 4) * 2048 * 8;

  floatx4 acc[4][4];
#pragma unroll
  for (int i = 0; i < 4; i++)
#pragma unroll
    for (int j = 0; j < 4; j++) acc[i][j] = (floatx4){0.f, 0.f, 0.f, 0.f};
  floatx4 accG[4];  // gram accumulators (A-rows if wm==wn else B-rows)
#pragma unroll
  for (int i = 0; i < 4; i++) accG[i] = (floatx4){0.f, 0.f, 0.f, 0.f};

  const int wm = wave >> 1;
  const int wn = wave & 1;
  const int quad = lane >> 4;
  const int l15 = lane & 15;
  const bool gramA = (wm == wn);

  // A staging map: 16B unit s = j*256 + tid; row = s>>4 (16 units/row);
  // slot = s&15 holds logical block (slot ^ (row&15)).
  int aoff[8];
#pragma unroll
  for (int j = 0; j < 8; j++) {
    int s = j * 256 + tid;
    int row = s >> 4;
    int blk = (s & 15) ^ (row & 15);
    aoff[j] = row * DD + blk * 4;
  }

  for (int kt = 0; kt < DD / 64; ++kt) {
    // B DMA: 32 KB of pre-packed bf16 (covers k for kt, kt+1).
    if ((kt & 1) == 0) {
      const short* gB = Bbase + (size_t)(kt >> 1) * 2048 * 8;
#pragma unroll
      for (int j = 0; j < 8; j++) {
        // PER-LANE source: unit u = j*256 + wave*64 + lane (16 B each).
        __builtin_amdgcn_global_load_lds(
            (const __attribute__((address_space(1))) unsigned int*)(gB +
                (size_t)(j * 256 + wave * 64 + lane) * 8),
            (__attribute__((address_space(3))) unsigned int*)(sB +
                (size_t)(j * 256 + wave * 64) * 8),
            16, 0, 0);
      }
    }
    // A DMA for this kt.
#pragma unroll
    for (int j = 0; j < 8; j++) {
      __builtin_amdgcn_global_load_lds(
          (const __attribute__((address_space(1))) unsigned int*)(Abase +
              aoff[j] + kt * 64),
          (__attribute__((address_space(3))) unsigned int*)(sA +
              (j * 256 + wave * 64) * 4),
          16, 0, 0);
    }
    __syncthreads();

#pragma unroll
    for (int ks = 0; ks < 2; ks++) {
      short8 af[4], bfr[4];
      const int b0s = ks * 8 + quad * 2;  // A frag: first 16B f32 block
      const int bslot = (kt & 1) * 8 + ks * 4 + quad;  // B frag: bf16 slot
#pragma unroll
      for (int im = 0; im < 4; im++) {
        int row = wm * 64 + im * 16 + l15;
        int s0 = b0s ^ (row & 15);
        int s1 = (b0s + 1) ^ (row & 15);
        float4 f0 = *(const float4*)(sA + row * 64 + s0 * 4);
        float4 f1 = *(const float4*)(sA + row * 64 + s1 * 4);
        af[im] = cvt8(f0, f1);
      }
#pragma unroll
      for (int in = 0; in < 4; in++) {
        int row = wn * 64 + in * 16 + l15;
        int s = bslot ^ (row & 15);
        bfr[in] = *(const short8*)(sB + row * 128 + s * 8);
      }
#pragma unroll
      for (int im = 0; im < 4; im++)
#pragma unroll
        for (int in = 0; in < 4; in++)
          acc[im][in] = __builtin_amdgcn_mfma_f32_16x16x32_bf16(
              af[im], bfr[in], acc[im][in], 0, 0, 0);
      if (gramA) {
#pragma unroll
        for (int im = 0; im < 4; im++)
          accG[im] = __builtin_amdgcn_mfma_f32_16x16x32_bf16(
              af[im], af[im], accG[im], 0, 0, 0);
      } else {
#pragma unroll
        for (int in = 0; in < 4; in++)
          accG[in] = __builtin_amdgcn_mfma_f32_16x16x32_bf16(
              bfr[in], bfr[in], accG[in], 0, 0, 0);
      }
    }
    __syncthreads();
  }

  // Extract gram diagonals -> inverse norms. C/D layout: col = l15,
  // row = quad*4 + r; diagonal element d: lane with l15==d, quad==d>>2,
  // reg r = d&3.
  if (quad == (l15 >> 2)) {
#pragma unroll
    for (int i = 0; i < 4; i++) {
      float inv = 1.0f / fmaxf(sqrtf(accG[i][l15 & 3]), 1e-8f);
      if (gramA)
        scX[wm * 64 + i * 16 + l15] = inv;  // waves (0,0),(1,1): rows 0..127
      else
        scY[wn * 64 + i * 16 + l15] = inv;  // waves (0,1),(1,0): cols 0..127
    }
  }
  __syncthreads();

  // Epilogue: apply cosine scales (dot * (1/||x||) * (1/||y||)).
  float* Obase = out + ((size_t)b * TT + tm * 128) * SS + tn * 128;
#pragma unroll
  for (int im = 0; im < 4; im++) {
#pragma unroll
    for (int in = 0; in < 4; in++) {
      int col = wn * 64 + in * 16 + l15;
      float yv = scY[col];
#pragma unroll
      for (int r = 0; r < 4; r++) {
        int row = wm * 64 + im * 16 + quad * 4 + r;
        Obase[row * SS + col] = acc[im][in][r] * scX[row] * yv;
      }
    }
  }
}

extern "C" void kernel_launch(void* const* d_in, const int* in_sizes, int n_in,
                              void* d_out, int out_size, void* d_ws,
                              size_t ws_size, hipStream_t stream) {
  const float* xs = (const float*)d_in[0];   // (8,4096,512) f32
  const float* spk = (const float*)d_in[1];  // (8,256,512) f32
  float* out = (float*)d_out;                // (8,4096,256) f32
  short* bp = (short*)d_ws;                  // 2 MB packed bf16 B

  hipLaunchKernelGGL(cos_packB_kernel, dim3(64), dim3(256), 0, stream, spk,
                     bp);
  hipLaunchKernelGGL(cos_fused_kernel, dim3(SS / 128, TT / 128, BB), dim3(256),
                     0, stream, xs, bp, out);
}